// Round 1
// baseline (1061.416 us; speedup 1.0000x reference)
//
#include <hip/hip_runtime.h>

typedef _Float16 half8 __attribute__((ext_vector_type(8)));
typedef _Float16 half4v __attribute__((ext_vector_type(4)));
typedef float floatx4 __attribute__((ext_vector_type(4)));

#define MFMA16(a, b, c) __builtin_amdgcn_mfma_f32_16x16x32_f16((a), (b), (c), 0, 0, 0)

// ws layout (units: _Float16 elements)
#define OFF_W1 0        // [mat2][nt6][ks24][lane64][8]  -> 147456 halves
#define OFF_W2 147456   // [mat2][nt3][ks3][64][8]       -> 9216
#define OFF_W3 156672   // [mat2][nt2][ks2][64][8]       -> 4096
#define OFF_W4 160768   // [mat2][64][8]                 -> 1024
#define OFF_W5 161792   // [mat2][64][8]                 -> 1024
// total 162816 halves = 325632 bytes of d_ws

// ---------------------------------------------------------------------------
// Prep: convert fp32 weights [N x K] into fp16 MFMA B-fragment layout.
// B[k][n] = W[n][k]; fragment lane l holds k = ks*32 + (l>>4)*8 + j, n = nt*16 + (l&15).
// Out-of-range (zero-pad) entries written as 0.
// ---------------------------------------------------------------------------
__global__ __launch_bounds__(64) void prep_weights(
    const float* __restrict__ eW1, const float* __restrict__ sW1,
    const float* __restrict__ eW2, const float* __restrict__ sW2,
    const float* __restrict__ eW3, const float* __restrict__ sW3,
    const float* __restrict__ eW4, const float* __restrict__ sW4,
    const float* __restrict__ eW5, const float* __restrict__ sW5,
    _Float16* __restrict__ ws)
{
    int b = blockIdx.x;
    int lane = threadIdx.x;
    const float* src;
    _Float16* dst;
    int N, K, nt, ks;
    if (b < 288) {
        int mat = b / 144, r = b % 144;
        nt = r / 24; ks = r % 24;
        src = mat ? sW1 : eW1; N = 96; K = 768;
        dst = ws + OFF_W1 + (size_t)((mat * 6 + nt) * 24 + ks) * 512;
    } else if (b < 306) {
        int i = b - 288, mat = i / 9, r = i % 9;
        nt = r / 3; ks = r % 3;
        src = mat ? sW2 : eW2; N = 48; K = 96;
        dst = ws + OFF_W2 + (size_t)((mat * 3 + nt) * 3 + ks) * 512;
    } else if (b < 314) {
        int i = b - 306, mat = i / 4, r = i % 4;
        nt = r / 2; ks = r % 2;
        src = mat ? sW3 : eW3; N = 24; K = 48;
        dst = ws + OFF_W3 + (size_t)((mat * 2 + nt) * 2 + ks) * 512;
    } else if (b < 316) {
        int mat = b - 314;
        nt = 0; ks = 0;
        src = mat ? sW4 : eW4; N = 12; K = 24;
        dst = ws + OFF_W4 + (size_t)mat * 512;
    } else {
        int mat = b - 316;
        nt = 0; ks = 0;
        src = mat ? sW5 : eW5; N = mat ? 2 : 8; K = 12;
        dst = ws + OFF_W5 + (size_t)mat * 512;
    }
    int n = nt * 16 + (lane & 15);
    int kb = ks * 32 + (lane >> 4) * 8;
    for (int j = 0; j < 8; ++j) {
        int k = kb + j;
        float v = (n < N && k < K) ? src[n * K + k] : 0.0f;
        dst[lane * 8 + j] = (_Float16)v;
    }
}

// ---------------------------------------------------------------------------
// Main fused kernel. Block = 256 threads = 4 waves, 32 samples.
// Wave w: mat = w>>1 (0=e branch, 1=s branch), mh = w&1 (0=pair rows, 1=seq rows).
// GEMM rows within a matrix: 0..31 = pair samples, 32..63 = seq samples.
// ---------------------------------------------------------------------------
__global__ __launch_bounds__(256) void fused_net(
    const float* __restrict__ result,
    const float* __restrict__ e_pair, const float* __restrict__ s_pair,
    const float* __restrict__ e_seq,  const float* __restrict__ s_seq,
    const float* __restrict__ cross_w,
    const _Float16* __restrict__ ws,
    float* __restrict__ out)
{
    // LDS: bufA (9216 h = 18432 B) | bufB (13312 h = 26624 B) | Eo (2048 B) | So (512 B)
    __shared__ __align__(16) unsigned char lds_raw[18432 + 26624 + 2048 + 512];
    _Float16* bufA = (_Float16*)lds_raw;
    _Float16* bufB = (_Float16*)(lds_raw + 18432);
    float* EoLDS = (float*)(lds_raw + 18432 + 26624);          // [64][8]
    float* SoLDS = (float*)(lds_raw + 18432 + 26624 + 2048);   // [64][2]

    const int tid  = threadIdx.x;
    const int lane = tid & 63;
    const int wave = tid >> 6;
    const int l15  = lane & 15;
    const int q    = lane >> 4;
    const int mat  = wave >> 1;   // 0 = e, 1 = s
    const int mh   = wave & 1;    // 0 = pair rows, 1 = seq rows
    const int sbase = blockIdx.x * 32;

    const float ep0 = e_pair[0], ep1 = e_pair[1];
    const float sp0 = s_pair[0], sp1 = s_pair[1];
    const float es0 = e_seq[0], es1 = e_seq[1], es2 = e_seq[2], es3 = e_seq[3];
    const float ss0 = s_seq[0], ss1 = s_seq[1], ss2 = s_seq[2], ss3 = s_seq[3];

    const floatx4 zf4 = {0.f, 0.f, 0.f, 0.f};

    // ---------------- Phase 1: layer-1 GEMM (K=768, N=96 per matrix) ----------
    floatx4 acc[2][6];
#pragma unroll
    for (int m = 0; m < 2; ++m)
#pragma unroll
        for (int n = 0; n < 6; ++n) acc[m][n] = zf4;

    const int kq = tid & 15;   // k-quad within 64-chunk (4 floats each)
    const int sg = tid >> 4;   // sample group 0..15
    _Float16* Am = bufA + mat * 4608;  // this wave's A matrix (stride 72 halves/row)
    const half8* Bw1 = (const half8*)(ws + OFF_W1) + (size_t)mat * 6 * 24 * 64;

    for (int c = 0; c < 12; ++c) {
        // ---- stage chunk c: 32 samples x 4 slots x 64 k, pooled + relu + fp16
#pragma unroll
        for (int pass = 0; pass < 2; ++pass) {
            int s = pass * 16 + sg;
            const float4* rp = (const float4*)(result + (size_t)(sbase + s) * 3072 + c * 64);
            float4 r0 = rp[kq];
            float4 r1 = rp[kq + 192];
            float4 r2 = rp[kq + 384];
            float4 r3 = rp[kq + 576];

            float pex = fmaxf(ep0 * r0.x + ep1 * r2.x, 0.f);
            float pey = fmaxf(ep0 * r0.y + ep1 * r2.y, 0.f);
            float pez = fmaxf(ep0 * r0.z + ep1 * r2.z, 0.f);
            float pew = fmaxf(ep0 * r0.w + ep1 * r2.w, 0.f);
            float psx = fmaxf(sp0 * r0.x + sp1 * r2.x, 0.f);
            float psy = fmaxf(sp0 * r0.y + sp1 * r2.y, 0.f);
            float psz = fmaxf(sp0 * r0.z + sp1 * r2.z, 0.f);
            float psw = fmaxf(sp0 * r0.w + sp1 * r2.w, 0.f);
            float sex = fmaxf(es0 * r0.x + es1 * r1.x + es2 * r2.x + es3 * r3.x, 0.f);
            float sey = fmaxf(es0 * r0.y + es1 * r1.y + es2 * r2.y + es3 * r3.y, 0.f);
            float sez = fmaxf(es0 * r0.z + es1 * r1.z + es2 * r2.z + es3 * r3.z, 0.f);
            float sew = fmaxf(es0 * r0.w + es1 * r1.w + es2 * r2.w + es3 * r3.w, 0.f);
            float ssx = fmaxf(ss0 * r0.x + ss1 * r1.x + ss2 * r2.x + ss3 * r3.x, 0.f);
            float ssy = fmaxf(ss0 * r0.y + ss1 * r1.y + ss2 * r2.y + ss3 * r3.y, 0.f);
            float ssz = fmaxf(ss0 * r0.z + ss1 * r1.z + ss2 * r2.z + ss3 * r3.z, 0.f);
            float ssw = fmaxf(ss0 * r0.w + ss1 * r1.w + ss2 * r2.w + ss3 * r3.w, 0.f);

            half4v hpe = {(_Float16)pex, (_Float16)pey, (_Float16)pez, (_Float16)pew};
            half4v hps = {(_Float16)psx, (_Float16)psy, (_Float16)psz, (_Float16)psw};
            half4v hse = {(_Float16)sex, (_Float16)sey, (_Float16)sez, (_Float16)sew};
            half4v hss = {(_Float16)ssx, (_Float16)ssy, (_Float16)ssz, (_Float16)ssw};

            int co = kq * 4;
            *(half4v*)(bufA + s * 72 + co)               = hpe;  // A_e pair
            *(half4v*)(bufA + (32 + s) * 72 + co)        = hse;  // A_e seq
            *(half4v*)(bufA + 4608 + s * 72 + co)        = hps;  // A_s pair
            *(half4v*)(bufA + 4608 + (32 + s) * 72 + co) = hss;  // A_s seq
        }
        __syncthreads();

        // ---- MFMA over the 2 k-steps of this chunk
#pragma unroll
        for (int ks2 = 0; ks2 < 2; ++ks2) {
            int kg = c * 2 + ks2;  // global k-step 0..23
            half8 a0 = *(const half8*)(Am + (mh * 32 + l15) * 72 + ks2 * 32 + q * 8);
            half8 a1 = *(const half8*)(Am + (mh * 32 + 16 + l15) * 72 + ks2 * 32 + q * 8);
#pragma unroll
            for (int nt = 0; nt < 6; ++nt) {
                half8 b = Bw1[(nt * 24 + kg) * 64 + lane];
                acc[0][nt] = MFMA16(a0, b, acc[0][nt]);
                acc[1][nt] = MFMA16(a1, b, acc[1][nt]);
            }
        }
        __syncthreads();
    }

    // ---------------- Phase 2: write relu(Y1) as fp16 to bufB (stride 104) ----
    _Float16* Y1h = bufB;
#pragma unroll
    for (int m = 0; m < 2; ++m)
#pragma unroll
        for (int nt = 0; nt < 6; ++nt)
#pragma unroll
            for (int r = 0; r < 4; ++r) {
                int row = mat * 64 + mh * 32 + m * 16 + q * 4 + r;
                Y1h[row * 104 + nt * 16 + l15] = (_Float16)fmaxf(acc[m][nt][r], 0.f);
            }
    __syncthreads();

    // ---------------- Phase 3: layer-2 (96 -> 48) --------------------------
    floatx4 acc2[2][3];
#pragma unroll
    for (int m = 0; m < 2; ++m)
#pragma unroll
        for (int n = 0; n < 3; ++n) acc2[m][n] = zf4;
    {
        const _Float16* A2 = Y1h + mat * 64 * 104;
        const half8* Bw2 = (const half8*)(ws + OFF_W2) + (size_t)mat * 3 * 3 * 64;
#pragma unroll
        for (int ks2 = 0; ks2 < 3; ++ks2) {
            half8 a0 = *(const half8*)(A2 + (mh * 32 + l15) * 104 + ks2 * 32 + q * 8);
            half8 a1 = *(const half8*)(A2 + (mh * 32 + 16 + l15) * 104 + ks2 * 32 + q * 8);
#pragma unroll
            for (int nt = 0; nt < 3; ++nt) {
                half8 b = Bw2[(nt * 3 + ks2) * 64 + lane];
                acc2[0][nt] = MFMA16(a0, b, acc2[0][nt]);
                acc2[1][nt] = MFMA16(a1, b, acc2[1][nt]);
            }
        }
    }
    // write relu(Y2) to bufA (stride 72), zero-pad cols 48..63
    _Float16* Y2h = bufA;
#pragma unroll
    for (int m = 0; m < 2; ++m)
#pragma unroll
        for (int nt = 0; nt < 3; ++nt)
#pragma unroll
            for (int r = 0; r < 4; ++r) {
                int row = mat * 64 + mh * 32 + m * 16 + q * 4 + r;
                Y2h[row * 72 + nt * 16 + l15] = (_Float16)fmaxf(acc2[m][nt][r], 0.f);
            }
    for (int i = tid; i < 2048; i += 256) {
        int row = i >> 4;
        Y2h[row * 72 + 48 + (i & 15)] = (_Float16)0.f;
    }
    __syncthreads();

    // ---------------- Phase 4: layer-3 (48 -> 24), K padded to 64 ----------
    floatx4 acc3[2][2];
#pragma unroll
    for (int m = 0; m < 2; ++m)
#pragma unroll
        for (int n = 0; n < 2; ++n) acc3[m][n] = zf4;
    {
        const _Float16* A3 = bufA + mat * 64 * 72;
        const half8* Bw3 = (const half8*)(ws + OFF_W3) + (size_t)mat * 2 * 2 * 64;
#pragma unroll
        for (int ks2 = 0; ks2 < 2; ++ks2) {
            half8 a0 = *(const half8*)(A3 + (mh * 32 + l15) * 72 + ks2 * 32 + q * 8);
            half8 a1 = *(const half8*)(A3 + (mh * 32 + 16 + l15) * 72 + ks2 * 32 + q * 8);
#pragma unroll
            for (int nt = 0; nt < 2; ++nt) {
                half8 b = Bw3[(nt * 2 + ks2) * 64 + lane];
                acc3[0][nt] = MFMA16(a0, b, acc3[0][nt]);
                acc3[1][nt] = MFMA16(a1, b, acc3[1][nt]);
            }
        }
    }
    // write relu(Y3) to bufB (stride 40); cols 24..31 are auto-zero (B-pad)
    _Float16* Y3h = bufB;
#pragma unroll
    for (int m = 0; m < 2; ++m)
#pragma unroll
        for (int nt = 0; nt < 2; ++nt)
#pragma unroll
            for (int r = 0; r < 4; ++r) {
                int row = mat * 64 + mh * 32 + m * 16 + q * 4 + r;
                Y3h[row * 40 + nt * 16 + l15] = (_Float16)fmaxf(acc3[m][nt][r], 0.f);
            }
    __syncthreads();

    // ---------------- Phase 5: layer-4 (24 -> 12), K padded to 32 ----------
    floatx4 acc4[2];
    {
        const _Float16* A4 = bufB + mat * 64 * 40;
        const half8* Bw4 = (const half8*)(ws + OFF_W4) + (size_t)mat * 64;
        half8 a0 = *(const half8*)(A4 + (mh * 32 + l15) * 40 + q * 8);
        half8 a1 = *(const half8*)(A4 + (mh * 32 + 16 + l15) * 40 + q * 8);
        half8 b = Bw4[lane];
        acc4[0] = MFMA16(a0, b, zf4);
        acc4[1] = MFMA16(a1, b, zf4);
    }
    // write relu(Y4) to bufA (stride 40); cols 12..15 auto-zero; fill 16..31
    _Float16* Y4h = bufA;
#pragma unroll
    for (int m = 0; m < 2; ++m)
#pragma unroll
        for (int r = 0; r < 4; ++r) {
            int row = mat * 64 + mh * 32 + m * 16 + q * 4 + r;
            Y4h[row * 40 + l15] = (_Float16)fmaxf(acc4[m][r], 0.f);
        }
    for (int i = tid; i < 2048; i += 256) {
        int row = i >> 4;
        Y4h[row * 40 + 16 + (i & 15)] = (_Float16)0.f;
    }
    __syncthreads();

    // ---------------- Phase 6: layer-5 (12 -> 8 or 2), K padded to 32 -------
    floatx4 acc5[2];
    {
        const _Float16* A5 = bufA + mat * 64 * 40;
        const half8* Bw5 = (const half8*)(ws + OFF_W5) + (size_t)mat * 64;
        half8 a0 = *(const half8*)(A5 + (mh * 32 + l15) * 40 + q * 8);
        half8 a1 = *(const half8*)(A5 + (mh * 32 + 16 + l15) * 40 + q * 8);
        half8 b = Bw5[lane];
        acc5[0] = MFMA16(a0, b, zf4);
        acc5[1] = MFMA16(a1, b, zf4);
    }
    if (mat == 0) {
        if (l15 < 8) {
#pragma unroll
            for (int m = 0; m < 2; ++m)
#pragma unroll
                for (int r = 0; r < 4; ++r) {
                    int row = mh * 32 + m * 16 + q * 4 + r;  // 0..31 pair, 32..63 seq
                    EoLDS[row * 8 + l15] = acc5[m][r];
                }
        }
    } else {
        if (l15 < 2) {
#pragma unroll
            for (int m = 0; m < 2; ++m)
#pragma unroll
                for (int r = 0; r < 4; ++r) {
                    int row = mh * 32 + m * 16 + q * 4 + r;
                    SoLDS[row * 2 + l15] = acc5[m][r];
                }
        }
    }
    __syncthreads();

    // ---------------- Phase 7: cross-mul + combine, write output ------------
    if (tid < 64) {
        int sample = tid >> 1;
        int h = tid & 1;
        float cw0 = cross_w[0], cw1 = cross_w[1];
        float pes = 0.f, ses = 0.f;
#pragma unroll
        for (int j = 0; j < 8; ++j) {
            pes += EoLDS[sample * 8 + j];
            ses += EoLDS[(32 + sample) * 8 + j];
        }
        float v = cw0 * SoLDS[sample * 2 + h] * pes
                + cw1 * SoLDS[(32 + sample) * 2 + h] * ses;
        out[(size_t)(sbase + sample) * 2 + h] = v;
    }
}

extern "C" void kernel_launch(void* const* d_in, const int* in_sizes, int n_in,
                              void* d_out, int out_size, void* d_ws, size_t ws_size,
                              hipStream_t stream) {
    (void)n_in; (void)out_size; (void)ws_size;
    const float* result = (const float*)d_in[0];
    const float* sW1 = (const float*)d_in[1];
    const float* sW2 = (const float*)d_in[2];
    const float* sW3 = (const float*)d_in[3];
    const float* sW4 = (const float*)d_in[4];
    const float* sW5 = (const float*)d_in[5];
    const float* eW1 = (const float*)d_in[6];
    const float* eW2 = (const float*)d_in[7];
    const float* eW3 = (const float*)d_in[8];
    const float* eW4 = (const float*)d_in[9];
    const float* eW5 = (const float*)d_in[10];
    const float* s_seq  = (const float*)d_in[11];
    const float* s_pair = (const float*)d_in[12];
    const float* e_seq  = (const float*)d_in[13];
    const float* e_pair = (const float*)d_in[14];
    const float* cross_w = (const float*)d_in[15];
    _Float16* ws = (_Float16*)d_ws;
    float* out = (float*)d_out;

    int B = in_sizes[0] / 3072;   // 65536

    prep_weights<<<dim3(318), dim3(64), 0, stream>>>(
        eW1, sW1, eW2, sW2, eW3, sW3, eW4, sW4, eW5, sW5, ws);

    fused_net<<<dim3(B / 32), dim3(256), 0, stream>>>(
        result, e_pair, s_pair, e_seq, s_seq, cross_w, ws, out);
}

// Round 2
// 1060.852 us; speedup vs baseline: 1.0005x; 1.0005x over previous
//
#include <hip/hip_runtime.h>

typedef _Float16 half8 __attribute__((ext_vector_type(8)));
typedef float floatx4 __attribute__((ext_vector_type(4)));

#define MFMA16(a, b, c) __builtin_amdgcn_mfma_f32_16x16x32_f16((a), (b), (c), 0, 0, 0)

// ws layout (units: _Float16 elements)
#define OFF_W1 0        // [mat2][nt6][ks24][lane64][8]  -> 147456 halves
#define OFF_W2 147456   // [mat2][nt3][ks3][64][8]       -> 9216
#define OFF_W3 156672   // [mat2][nt2][ks2][64][8]       -> 4096
#define OFF_W4 160768   // [mat2][64][8]                 -> 1024
#define OFF_W5 161792   // [mat2][64][8]                 -> 1024

typedef __attribute__((address_space(3))) unsigned int lds_uint;
typedef __attribute__((address_space(1))) unsigned int glob_uint;

__device__ __forceinline__ void async_copy16(const void* g, void* l) {
    // each lane: 16 B from its global addr -> LDS base + lane*16 (base wave-uniform)
    __builtin_amdgcn_global_load_lds((const glob_uint*)g, (lds_uint*)l, 16, 0, 0);
}

// ---------------------------------------------------------------------------
// Prep: fp32 weights [N x K] -> fp16 MFMA B-fragment layout, zero-padded.
// ---------------------------------------------------------------------------
__global__ __launch_bounds__(64) void prep_weights(
    const float* __restrict__ eW1, const float* __restrict__ sW1,
    const float* __restrict__ eW2, const float* __restrict__ sW2,
    const float* __restrict__ eW3, const float* __restrict__ sW3,
    const float* __restrict__ eW4, const float* __restrict__ sW4,
    const float* __restrict__ eW5, const float* __restrict__ sW5,
    _Float16* __restrict__ ws)
{
    int b = blockIdx.x;
    int lane = threadIdx.x;
    const float* src;
    _Float16* dst;
    int N, K, nt, ks;
    if (b < 288) {
        int mat = b / 144, r = b % 144;
        nt = r / 24; ks = r % 24;
        src = mat ? sW1 : eW1; N = 96; K = 768;
        dst = ws + OFF_W1 + (size_t)((mat * 6 + nt) * 24 + ks) * 512;
    } else if (b < 306) {
        int i = b - 288, mat = i / 9, r = i % 9;
        nt = r / 3; ks = r % 3;
        src = mat ? sW2 : eW2; N = 48; K = 96;
        dst = ws + OFF_W2 + (size_t)((mat * 3 + nt) * 3 + ks) * 512;
    } else if (b < 314) {
        int i = b - 306, mat = i / 4, r = i % 4;
        nt = r / 2; ks = r % 2;
        src = mat ? sW3 : eW3; N = 24; K = 48;
        dst = ws + OFF_W3 + (size_t)((mat * 2 + nt) * 2 + ks) * 512;
    } else if (b < 316) {
        int mat = b - 314;
        nt = 0; ks = 0;
        src = mat ? sW4 : eW4; N = 12; K = 24;
        dst = ws + OFF_W4 + (size_t)mat * 512;
    } else {
        int mat = b - 316;
        nt = 0; ks = 0;
        src = mat ? sW5 : eW5; N = mat ? 2 : 8; K = 12;
        dst = ws + OFF_W5 + (size_t)mat * 512;
    }
    int n = nt * 16 + (lane & 15);
    int kb = ks * 32 + (lane >> 4) * 8;
    for (int j = 0; j < 8; ++j) {
        int k = kb + j;
        float v = (n < N && k < K) ? src[n * K + k] : 0.0f;
        dst[lane * 8 + j] = (_Float16)v;
    }
}

// ---------------------------------------------------------------------------
// Raw-chunk LDS addressing: chunk = 32 samples x 4 slots x 32 k (fp32).
// 1 KB DMA block = 2 samples; block stride 1040 B (16 B pad -> 2-way-max
// bank conflicts on 16B frag reads: bank quad = 4*(s>>1) + 8*q mod 32).
// addr(s,t,k16) = (s>>1)*1040 + (s&1)*512 + (t*8+k16)*16
// ---------------------------------------------------------------------------
__device__ __forceinline__ const float4* rawp(const unsigned char* buf, int s, int t, int k16) {
    return (const float4*)(buf + ((s >> 1) * 1040 + ((s & 1) << 9) + (((t << 3) | k16) << 4)));
}

__device__ __forceinline__ half8 frag_pair(const unsigned char* buf, int s, int q,
                                           float w0, float w1) {
    float4 a0 = *rawp(buf, s, 0, 2 * q);
    float4 a1 = *rawp(buf, s, 0, 2 * q + 1);
    float4 c0 = *rawp(buf, s, 2, 2 * q);
    float4 c1 = *rawp(buf, s, 2, 2 * q + 1);
    half8 h;
    h[0] = (_Float16)fmaxf(w0 * a0.x + w1 * c0.x, 0.f);
    h[1] = (_Float16)fmaxf(w0 * a0.y + w1 * c0.y, 0.f);
    h[2] = (_Float16)fmaxf(w0 * a0.z + w1 * c0.z, 0.f);
    h[3] = (_Float16)fmaxf(w0 * a0.w + w1 * c0.w, 0.f);
    h[4] = (_Float16)fmaxf(w0 * a1.x + w1 * c1.x, 0.f);
    h[5] = (_Float16)fmaxf(w0 * a1.y + w1 * c1.y, 0.f);
    h[6] = (_Float16)fmaxf(w0 * a1.z + w1 * c1.z, 0.f);
    h[7] = (_Float16)fmaxf(w0 * a1.w + w1 * c1.w, 0.f);
    return h;
}

__device__ __forceinline__ half8 frag_seq(const unsigned char* buf, int s, int q,
                                          float w0, float w1, float w2, float w3) {
    float4 a0 = *rawp(buf, s, 0, 2 * q);
    float4 a1 = *rawp(buf, s, 0, 2 * q + 1);
    float4 b0 = *rawp(buf, s, 1, 2 * q);
    float4 b1 = *rawp(buf, s, 1, 2 * q + 1);
    float4 c0 = *rawp(buf, s, 2, 2 * q);
    float4 c1 = *rawp(buf, s, 2, 2 * q + 1);
    float4 d0 = *rawp(buf, s, 3, 2 * q);
    float4 d1 = *rawp(buf, s, 3, 2 * q + 1);
    half8 h;
    h[0] = (_Float16)fmaxf(w0 * a0.x + w1 * b0.x + w2 * c0.x + w3 * d0.x, 0.f);
    h[1] = (_Float16)fmaxf(w0 * a0.y + w1 * b0.y + w2 * c0.y + w3 * d0.y, 0.f);
    h[2] = (_Float16)fmaxf(w0 * a0.z + w1 * b0.z + w2 * c0.z + w3 * d0.z, 0.f);
    h[3] = (_Float16)fmaxf(w0 * a0.w + w1 * b0.w + w2 * c0.w + w3 * d0.w, 0.f);
    h[4] = (_Float16)fmaxf(w0 * a1.x + w1 * b1.x + w2 * c1.x + w3 * d1.x, 0.f);
    h[5] = (_Float16)fmaxf(w0 * a1.y + w1 * b1.y + w2 * c1.y + w3 * d1.y, 0.f);
    h[6] = (_Float16)fmaxf(w0 * a1.z + w1 * b1.z + w2 * c1.z + w3 * d1.z, 0.f);
    h[7] = (_Float16)fmaxf(w0 * a1.w + w1 * b1.w + w2 * c1.w + w3 * d1.w, 0.f);
    return h;
}

// ---------------------------------------------------------------------------
// Fused net. Block = 256 threads = 4 waves, 32 samples.
// Wave w: mat = w>>1 (0=e,1=s), mh = w&1 (0=pair pooling rows, 1=seq rows).
// LDS: [0,33280) = 2 x 16640 raw double-buffer (phase 1), reused in-place for
// Y1 (stride 104) / Y2 (72) / Y3,Y4 (40) in phases 2+; Eo/So at 33280.
// Total 35840 B -> 4 blocks/CU; __launch_bounds__(256,4) pins VGPR<=128.
// ---------------------------------------------------------------------------
__global__ __launch_bounds__(256, 4) void fused_net(
    const float* __restrict__ result,
    const float* __restrict__ e_pair, const float* __restrict__ s_pair,
    const float* __restrict__ e_seq,  const float* __restrict__ s_seq,
    const float* __restrict__ cross_w,
    const _Float16* __restrict__ ws,
    float* __restrict__ out)
{
    __shared__ __align__(16) unsigned char lds_raw[35840];
    float* EoLDS = (float*)(lds_raw + 33280);         // [64][8]
    float* SoLDS = (float*)(lds_raw + 33280 + 2048);  // [64][2]

    const int tid  = threadIdx.x;
    const int lane = tid & 63;
    const int wave = tid >> 6;
    const int l15  = lane & 15;
    const int q    = lane >> 4;
    const int mat  = wave >> 1;   // 0 = e, 1 = s
    const int mh   = wave & 1;    // 0 = pair rows, 1 = seq rows
    const int sbase = blockIdx.x * 32;

    // wave-uniform pooling coefficients
    float w0, w1, w2 = 0.f, w3 = 0.f;
    if (mh == 0) {
        w0 = mat ? s_pair[0] : e_pair[0];
        w1 = mat ? s_pair[1] : e_pair[1];
    } else {
        w0 = mat ? s_seq[0] : e_seq[0];
        w1 = mat ? s_seq[1] : e_seq[1];
        w2 = mat ? s_seq[2] : e_seq[2];
        w3 = mat ? s_seq[3] : e_seq[3];
    }

    const floatx4 zf4 = {0.f, 0.f, 0.f, 0.f};

    // DMA lane mapping (fixed per thread): 1KB block -> 2 samples
    const int dma_so  = lane >> 5;        // sample parity within block
    const int dma_u   = lane & 31;        // 16B unit within sample's 512B
    const int dma_t   = dma_u >> 3;       // slot
    const int dma_k16 = dma_u & 7;        // 16B k-unit
    const size_t dma_goff = (size_t)(dma_t * 768 + dma_k16 * 4);

    // ---------------- Phase 1: layer-1 GEMM (K=768 -> 24 chunks of 32) ------
    floatx4 acc[2][6];
#pragma unroll
    for (int m = 0; m < 2; ++m)
#pragma unroll
        for (int n = 0; n < 6; ++n) acc[m][n] = zf4;

    const half8* Bw1 = (const half8*)(ws + OFF_W1) + (size_t)mat * (6 * 24 * 64);

    // preload chunk 0
    {
        const float* gbase = result + (size_t)sbase * 3072;
#pragma unroll
        for (int i = 0; i < 4; ++i) {
            int blk = wave * 4 + i;
            const float* g = gbase + (size_t)(2 * blk + dma_so) * 3072 + dma_goff;
            async_copy16(g, lds_raw + blk * 1040);
        }
    }
    __syncthreads();

#pragma unroll 2
    for (int c = 0; c < 24; ++c) {
        const unsigned char* cur = lds_raw + (c & 1) * 16640;
        unsigned char* nxt = lds_raw + ((c + 1) & 1) * 16640;
        if (c < 23) {
            const float* gbase = result + (size_t)sbase * 3072 + (c + 1) * 32;
#pragma unroll
            for (int i = 0; i < 4; ++i) {
                int blk = wave * 4 + i;
                const float* g = gbase + (size_t)(2 * blk + dma_so) * 3072 + dma_goff;
                async_copy16(g, nxt + blk * 1040);
            }
        }
        half8 a0f, a1f;
        if (mh == 0) {
            a0f = frag_pair(cur, l15,      q, w0, w1);
            a1f = frag_pair(cur, l15 + 16, q, w0, w1);
        } else {
            a0f = frag_seq(cur, l15,      q, w0, w1, w2, w3);
            a1f = frag_seq(cur, l15 + 16, q, w0, w1, w2, w3);
        }
#pragma unroll
        for (int nt = 0; nt < 6; ++nt) {
            half8 bf = Bw1[(nt * 24 + c) * 64 + lane];
            acc[0][nt] = MFMA16(a0f, bf, acc[0][nt]);
            acc[1][nt] = MFMA16(a1f, bf, acc[1][nt]);
        }
        __syncthreads();   // drains vmcnt -> chunk c+1 resident; raw reuse safe
    }

    _Float16* Y = (_Float16*)lds_raw;

    // ---------------- Phase 2: Y1 = relu(L1) fp16, stride 104 ---------------
#pragma unroll
    for (int m = 0; m < 2; ++m)
#pragma unroll
        for (int nt = 0; nt < 6; ++nt)
#pragma unroll
            for (int r = 0; r < 4; ++r) {
                int row = mat * 64 + mh * 32 + m * 16 + q * 4 + r;
                Y[row * 104 + nt * 16 + l15] = (_Float16)fmaxf(acc[m][nt][r], 0.f);
            }
    __syncthreads();

    // ---------------- Phase 3: layer-2 (96 -> 48) ---------------------------
    floatx4 acc2[2][3];
#pragma unroll
    for (int m = 0; m < 2; ++m)
#pragma unroll
        for (int n = 0; n < 3; ++n) acc2[m][n] = zf4;
    {
        const _Float16* A2 = Y + mat * 64 * 104;
        const half8* Bw2 = (const half8*)(ws + OFF_W2) + (size_t)mat * (3 * 3 * 64);
#pragma unroll
        for (int ks2 = 0; ks2 < 3; ++ks2) {
            half8 a0 = *(const half8*)(A2 + (mh * 32 + l15) * 104 + ks2 * 32 + q * 8);
            half8 a1 = *(const half8*)(A2 + (mh * 32 + 16 + l15) * 104 + ks2 * 32 + q * 8);
#pragma unroll
            for (int nt = 0; nt < 3; ++nt) {
                half8 bf = Bw2[(nt * 3 + ks2) * 64 + lane];
                acc2[0][nt] = MFMA16(a0, bf, acc2[0][nt]);
                acc2[1][nt] = MFMA16(a1, bf, acc2[1][nt]);
            }
        }
    }
    __syncthreads();   // all Y1 reads done before overwrite
    // write Y2 stride 72, zero-pad cols 48..63
#pragma unroll
    for (int m = 0; m < 2; ++m)
#pragma unroll
        for (int nt = 0; nt < 3; ++nt)
#pragma unroll
            for (int r = 0; r < 4; ++r) {
                int row = mat * 64 + mh * 32 + m * 16 + q * 4 + r;
                Y[row * 72 + nt * 16 + l15] = (_Float16)fmaxf(acc2[m][nt][r], 0.f);
            }
    for (int i = tid; i < 2048; i += 256) {
        int row = i >> 4;
        Y[row * 72 + 48 + (i & 15)] = (_Float16)0.f;
    }
    __syncthreads();

    // ---------------- Phase 4: layer-3 (48 -> 24), K padded to 64 -----------
    floatx4 acc3[2][2];
#pragma unroll
    for (int m = 0; m < 2; ++m)
#pragma unroll
        for (int n = 0; n < 2; ++n) acc3[m][n] = zf4;
    {
        const _Float16* A3 = Y + mat * 64 * 72;
        const half8* Bw3 = (const half8*)(ws + OFF_W3) + (size_t)mat * (2 * 2 * 64);
#pragma unroll
        for (int ks2 = 0; ks2 < 2; ++ks2) {
            half8 a0 = *(const half8*)(A3 + (mh * 32 + l15) * 72 + ks2 * 32 + q * 8);
            half8 a1 = *(const half8*)(A3 + (mh * 32 + 16 + l15) * 72 + ks2 * 32 + q * 8);
#pragma unroll
            for (int nt = 0; nt < 2; ++nt) {
                half8 bf = Bw3[(nt * 2 + ks2) * 64 + lane];
                acc3[0][nt] = MFMA16(a0, bf, acc3[0][nt]);
                acc3[1][nt] = MFMA16(a1, bf, acc3[1][nt]);
            }
        }
    }
    __syncthreads();
    // write Y3 stride 40, zero-pad cols 24..31
#pragma unroll
    for (int m = 0; m < 2; ++m)
#pragma unroll
        for (int nt = 0; nt < 2; ++nt)
#pragma unroll
            for (int r = 0; r < 4; ++r) {
                int row = mat * 64 + mh * 32 + m * 16 + q * 4 + r;
                Y[row * 40 + nt * 16 + l15] = (_Float16)fmaxf(acc3[m][nt][r], 0.f);
            }
    for (int i = tid; i < 1024; i += 256) {
        int row = i >> 3;
        Y[row * 40 + 24 + (i & 7)] = (_Float16)0.f;
    }
    __syncthreads();

    // ---------------- Phase 5: layer-4 (24 -> 12), K padded to 32 -----------
    floatx4 acc4[2];
    {
        const _Float16* A4 = Y + mat * 64 * 40;
        const half8* Bw4 = (const half8*)(ws + OFF_W4) + (size_t)mat * 64;
        half8 a0 = *(const half8*)(A4 + (mh * 32 + l15) * 40 + q * 8);
        half8 a1 = *(const half8*)(A4 + (mh * 32 + 16 + l15) * 40 + q * 8);
        half8 bf = Bw4[lane];
        acc4[0] = MFMA16(a0, bf, zf4);
        acc4[1] = MFMA16(a1, bf, zf4);
    }
    __syncthreads();
    // write Y4 stride 40, zero-pad cols 12..31
#pragma unroll
    for (int m = 0; m < 2; ++m)
#pragma unroll
        for (int r = 0; r < 4; ++r) {
            int row = mat * 64 + mh * 32 + m * 16 + q * 4 + r;
            Y[row * 40 + l15] = (_Float16)fmaxf(acc4[m][r], 0.f);
        }
    for (int i = tid; i < 2560; i += 256) {
        int row = i / 20;
        Y[row * 40 + 12 + (i % 20)] = (_Float16)0.f;
    }
    __syncthreads();

    // ---------------- Phase 6: layer-5 (12 -> 8 or 2), K padded to 32 -------
    floatx4 acc5[2];
    {
        const _Float16* A5 = Y + mat * 64 * 40;
        const half8* Bw5 = (const half8*)(ws + OFF_W5) + (size_t)mat * 64;
        half8 a0 = *(const half8*)(A5 + (mh * 32 + l15) * 40 + q * 8);
        half8 a1 = *(const half8*)(A5 + (mh * 32 + 16 + l15) * 40 + q * 8);
        half8 bf = Bw5[lane];
        acc5[0] = MFMA16(a0, bf, zf4);
        acc5[1] = MFMA16(a1, bf, zf4);
    }
    if (mat == 0) {
        if (l15 < 8) {
#pragma unroll
            for (int m = 0; m < 2; ++m)
#pragma unroll
                for (int r = 0; r < 4; ++r) {
                    int row = mh * 32 + m * 16 + q * 4 + r;  // 0..31 pair, 32..63 seq
                    EoLDS[row * 8 + l15] = acc5[m][r];
                }
        }
    } else {
        if (l15 < 2) {
#pragma unroll
            for (int m = 0; m < 2; ++m)
#pragma unroll
                for (int r = 0; r < 4; ++r) {
                    int row = mh * 32 + m * 16 + q * 4 + r;
                    SoLDS[row * 2 + l15] = acc5[m][r];
                }
        }
    }
    __syncthreads();

    // ---------------- Phase 7: cross-mul + combine --------------------------
    if (tid < 64) {
        int sample = tid >> 1;
        int h = tid & 1;
        float cw0 = cross_w[0], cw1 = cross_w[1];
        float pes = 0.f, ses = 0.f;
#pragma unroll
        for (int j = 0; j < 8; ++j) {
            pes += EoLDS[sample * 8 + j];
            ses += EoLDS[(32 + sample) * 8 + j];
        }
        float v = cw0 * SoLDS[sample * 2 + h] * pes
                + cw1 * SoLDS[(32 + sample) * 2 + h] * ses;
        out[(size_t)(sbase + sample) * 2 + h] = v;
    }
}

extern "C" void kernel_launch(void* const* d_in, const int* in_sizes, int n_in,
                              void* d_out, int out_size, void* d_ws, size_t ws_size,
                              hipStream_t stream) {
    (void)n_in; (void)out_size; (void)ws_size;
    const float* result = (const float*)d_in[0];
    const float* sW1 = (const float*)d_in[1];
    const float* sW2 = (const float*)d_in[2];
    const float* sW3 = (const float*)d_in[3];
    const float* sW4 = (const float*)d_in[4];
    const float* sW5 = (const float*)d_in[5];
    const float* eW1 = (const float*)d_in[6];
    const float* eW2 = (const float*)d_in[7];
    const float* eW3 = (const float*)d_in[8];
    const float* eW4 = (const float*)d_in[9];
    const float* eW5 = (const float*)d_in[10];
    const float* s_seq  = (const float*)d_in[11];
    const float* s_pair = (const float*)d_in[12];
    const float* e_seq  = (const float*)d_in[13];
    const float* e_pair = (const float*)d_in[14];
    const float* cross_w = (const float*)d_in[15];
    _Float16* ws = (_Float16*)d_ws;
    float* out = (float*)d_out;

    int B = in_sizes[0] / 3072;   // 65536

    prep_weights<<<dim3(318), dim3(64), 0, stream>>>(
        eW1, sW1, eW2, sW2, eW3, sW3, eW4, sW4, eW5, sW5, ws);

    fused_net<<<dim3(B / 32), dim3(256), 0, stream>>>(
        result, e_pair, s_pair, e_seq, s_seq, cross_w, ws, out);
}